// Round 8
// baseline (366.207 us; speedup 1.0000x reference)
//
#include <hip/hip_runtime.h>

typedef __bf16 bf16x8 __attribute__((ext_vector_type(8)));
typedef unsigned short u16x8 __attribute__((ext_vector_type(8)));
typedef unsigned short u16x4 __attribute__((ext_vector_type(4)));
typedef float f32x4 __attribute__((ext_vector_type(4)));

#define MFMA16(a, b, c) __builtin_amdgcn_mfma_f32_16x16x32_bf16((a), (b), (c), 0, 0, 0)

constexpr int SEQ  = 4096;
constexpr int DH   = 64;
constexpr int BH   = 16;     // B*H
constexpr int LSTR = 72;     // LDS row stride (ushorts) for Pt
constexpr float SCALE_LOG2E = 0.125f * 1.44269504088896f;  // 1/sqrt(64) * log2(e)

__device__ __forceinline__ unsigned short f2bf(float f) {
  unsigned int u = __float_as_uint(f);
  u += 0x7fffu + ((u >> 16) & 1u);   // RNE
  return (unsigned short)(u >> 16);
}

// ---------------- pre-pass: K fp32->bf16 copy; V fp32 -> V^T bf16 tiles (direct, no LDS) ----------------
__global__ __launch_bounds__(256)
void prep_9990093930993(const float* __restrict__ K, const float* __restrict__ V,
                        unsigned short* __restrict__ Kb, unsigned short* __restrict__ Vtb) {
  const int tile = blockIdx.x, bh = blockIdx.y, tid = threadIdx.x;

  // --- K: straight bf16 convert, layout unchanged [bh][S][64] ---
  {
    const int row = tid >> 2;          // 0..63
    const int c0  = (tid & 3) * 16;    // 0,16,32,48
    const float* kr = K + (((long)bh * SEQ + tile * 64) + row) * DH + c0;
    float4 x0 = *(const float4*)(kr);
    float4 x1 = *(const float4*)(kr + 4);
    float4 x2 = *(const float4*)(kr + 8);
    float4 x3 = *(const float4*)(kr + 12);
    u16x8 a, b;
    a[0]=f2bf(x0.x); a[1]=f2bf(x0.y); a[2]=f2bf(x0.z); a[3]=f2bf(x0.w);
    a[4]=f2bf(x1.x); a[5]=f2bf(x1.y); a[6]=f2bf(x1.z); a[7]=f2bf(x1.w);
    b[0]=f2bf(x2.x); b[1]=f2bf(x2.y); b[2]=f2bf(x2.z); b[3]=f2bf(x2.w);
    b[4]=f2bf(x3.x); b[5]=f2bf(x3.y); b[6]=f2bf(x3.z); b[7]=f2bf(x3.w);
    unsigned short* ko = Kb + (((long)bh * SEQ + tile * 64) + row) * DH + c0;
    *(u16x8*)ko = a;
    *(u16x8*)(ko + 8) = b;
  }

  // --- V: direct transpose. lane = d (coalesced reads), wave kg covers 16 keys ---
  {
    const int d  = tid & 63;
    const int kg = tid >> 6;           // 0..3
    const float* vp = V + ((long)bh * SEQ + tile * 64) * DH;
    unsigned short* op = Vtb + (((long)bh * 64 + tile) * 64 + d) * 64 + kg * 16;
    #pragma unroll
    for (int h = 0; h < 2; ++h) {
      u16x8 o;
      #pragma unroll
      for (int j = 0; j < 8; ++j)
        o[j] = f2bf(vp[(kg * 16 + h * 8 + j) * DH + d]);
      *(u16x8*)(op + h * 8) = o;
    }
  }
}

// ---------------- main attention: NO K/V staging (L2/L3-resident), barrier-free, balanced grid ----------------
// Grid = 768 blocks: qtiles 32..63 singles (two id-ranges), qtiles 0..31 paired {p,31-p}.
// LDS holds only the per-wave Pt round-trip (9 KB). K/V fragments read directly from
// the pre-converted global buffers at the exact addresses staging used to produce.
__global__ __launch_bounds__(256, 3)
void attn5_9990093930993(const float* __restrict__ Qg,
                         const unsigned short* __restrict__ Kb,
                         const unsigned short* __restrict__ Vtb,
                         float* __restrict__ Og) {
  __shared__ unsigned short Pt[4][16 * LSTR];

  const int tid  = threadIdx.x;
  const int wave = tid >> 6;
  const int lane = tid & 63;
  const int l16  = lane & 15;
  const int lg   = lane >> 4;

  // ---- decode balanced work assignment (bijection onto qtile 0..63 x bh 0..15) ----
  int nseg, qt0, qt1 = 0, bhi;
  {
    const int id = blockIdx.x;
    if (id < 256)      { nseg = 1; qt0 = 63 - (id >> 3); bhi = id & 7; }
    else if (id < 512) { const int j = id - 256; nseg = 2; const int p = j >> 4;
                         qt0 = 31 - p; qt1 = p; bhi = j & 15; }
    else               { const int j = id - 512; nseg = 1; qt0 = 32 + (j >> 3); bhi = 8 + (j & 7); }
  }
  const long bh = bhi;

  const float*          Qp = Qg  + bh * (long)(SEQ * DH);
  const unsigned short* Kp = Kb  + bh * (long)(SEQ * DH);
  const unsigned short* Vp = Vtb + bh * (long)(SEQ * DH);
  float*                Op = Og  + bh * (long)(SEQ * DH);

  // all-ones bf16 B-fragment: accl = P * ones -> row sums of P, same lane layout as oacc
  bf16x8 vone;
  {
    u16x8 t1;
    #pragma unroll
    for (int j = 0; j < 8; ++j) t1[j] = 0x3F80;
    vone = __builtin_bit_cast(bf16x8, t1);
  }

  #pragma unroll 1
  for (int seg = 0; seg < nseg; ++seg) {
    const int qt = (seg == 0) ? qt0 : qt1;
    const int qrow0 = qt * 64 + wave * 16;

    // Q fragments (inline fp32 -> bf16, scale*log2e folded); MFMA B-operand
    bf16x8 qf[2];
    {
      const float* qr = Qp + (long)(qrow0 + l16) * DH + lg * 8;
      #pragma unroll
      for (int s = 0; s < 2; ++s) {
        float4 a = *(const float4*)(qr + s * 32);
        float4 b = *(const float4*)(qr + s * 32 + 4);
        u16x8 t2;
        t2[0] = f2bf(a.x * SCALE_LOG2E); t2[1] = f2bf(a.y * SCALE_LOG2E);
        t2[2] = f2bf(a.z * SCALE_LOG2E); t2[3] = f2bf(a.w * SCALE_LOG2E);
        t2[4] = f2bf(b.x * SCALE_LOG2E); t2[5] = f2bf(b.y * SCALE_LOG2E);
        t2[6] = f2bf(b.z * SCALE_LOG2E); t2[7] = f2bf(b.w * SCALE_LOG2E);
        qf[s] = __builtin_bit_cast(bf16x8, t2);
      }
    }

    f32x4 oacc[4] = {};
    f32x4 accl    = {};

    #pragma unroll 1
    for (int t = 0; t <= qt; ++t) {
      const unsigned short* ks = Kp + (long)t * 4096;   // K tile [64][64]
      const unsigned short* vs = Vp + (long)t * 4096;   // V^T tile [64][64]

      // ---- preload V fragments (8 x u16x8, fully static indices -> registers);
      //      L2 latency hides under QK^T + softmax below ----
      u16x8 vreg[2][4];
      #pragma unroll
      for (int ks2 = 0; ks2 < 2; ++ks2)
        #pragma unroll
        for (int dt = 0; dt < 4; ++dt)
          vreg[ks2][dt] = *(const u16x8*)(vs + (dt * 16 + l16) * 64 + ks2 * 32 + lg * 8);

      // ---- S^T = K Q^T (swapped operands): lane holds S[q=l16][k = t*64+kt*16+lg*4+r] ----
      float sv[16];
      #pragma unroll
      for (int kt = 0; kt < 4; ++kt) {
        bf16x8 kf0 = __builtin_bit_cast(bf16x8, *(const u16x8*)(ks + (kt * 16 + l16) * 64 + lg * 8));
        bf16x8 kf1 = __builtin_bit_cast(bf16x8, *(const u16x8*)(ks + (kt * 16 + l16) * 64 + 32 + lg * 8));
        f32x4 st = {0.f, 0.f, 0.f, 0.f};
        st = MFMA16(kf0, qf[0], st);
        st = MFMA16(kf1, qf[1], st);
        #pragma unroll
        for (int r = 0; r < 4; ++r) sv[kt * 4 + r] = st[r];
      }
      if (t == qt) {   // diagonal tile mask: k > q
        const int qg = qrow0 + l16;
        #pragma unroll
        for (int kt = 0; kt < 4; ++kt) {
          const int k0 = t * 64 + kt * 16 + lg * 4;
          #pragma unroll
          for (int r = 0; r < 4; ++r)
            if (k0 + r > qg) sv[kt * 4 + r] = -1e30f;
        }
      }

      // ---- p = exp2(s); 4 k-consecutive bf16 per lane; one b64 LDS write per kt ----
      #pragma unroll
      for (int kt = 0; kt < 4; ++kt) {
        u16x4 w;
        w[0] = f2bf(__builtin_amdgcn_exp2f(sv[kt * 4 + 0]));
        w[1] = f2bf(__builtin_amdgcn_exp2f(sv[kt * 4 + 1]));
        w[2] = f2bf(__builtin_amdgcn_exp2f(sv[kt * 4 + 2]));
        w[3] = f2bf(__builtin_amdgcn_exp2f(sv[kt * 4 + 3]));
        *(u16x4*)&Pt[wave][l16 * LSTR + kt * 16 + lg * 4] = w;
      }

      // ---- O += P V ; lsum += P * ones (same-wave Pt round-trip, no barrier needed) ----
      #pragma unroll
      for (int ks2 = 0; ks2 < 2; ++ks2) {
        bf16x8 pf = __builtin_bit_cast(bf16x8, *(const u16x8*)&Pt[wave][l16 * LSTR + ks2 * 32 + lg * 8]);
        accl = MFMA16(pf, vone, accl);
        #pragma unroll
        for (int dt = 0; dt < 4; ++dt) {
          bf16x8 vf = __builtin_bit_cast(bf16x8, vreg[ks2][dt]);
          oacc[dt] = MFMA16(pf, vf, oacc[dt]);
        }
      }
    }

    // ---- epilogue: normalize by row-sum and store ----
    #pragma unroll
    for (int r = 0; r < 4; ++r) {
      const float inv = 1.0f / accl[r];
      float* orow = Op + (long)(qrow0 + lg * 4 + r) * DH + l16;
      #pragma unroll
      for (int dt = 0; dt < 4; ++dt)
        orow[dt * 16] = oacc[dt][r] * inv;
    }
  }
}

// ---------------- fallback (fp32 direct, if workspace too small) ----------------
__global__ __launch_bounds__(256, 2)
void attn_fwd_fb_9990093930993(const float* __restrict__ Qg, const float* __restrict__ Kg,
                               const float* __restrict__ Vg, float* __restrict__ Og) {
  constexpr int FSTR = 88;
  __shared__ unsigned short Kt[64 * FSTR];
  __shared__ unsigned short Vt[64 * FSTR];
  __shared__ unsigned short Pt[4][16 * FSTR];
  const int tid = threadIdx.x, wave = tid >> 6, lane = tid & 63;
  const int l16 = lane & 15, lg = lane >> 4;
  const int qtile = blockIdx.x; const long bh = blockIdx.y;
  const float* Qp = Qg + bh * (long)(SEQ * DH);
  const float* Kp = Kg + bh * (long)(SEQ * DH);
  const float* Vp = Vg + bh * (long)(SEQ * DH);
  float* Op = Og + bh * (long)(SEQ * DH);
  const int qrow0 = qtile * 64 + wave * 16;
  bf16x8 qf[2];
  {
    const float* qr = Qp + (long)(qrow0 + l16) * DH + lg * 8;
    #pragma unroll
    for (int s = 0; s < 2; ++s) {
      float4 a = *(const float4*)(qr + s * 32);
      float4 b = *(const float4*)(qr + s * 32 + 4);
      u16x8 t2;
      t2[0]=f2bf(a.x*0.125f); t2[1]=f2bf(a.y*0.125f); t2[2]=f2bf(a.z*0.125f); t2[3]=f2bf(a.w*0.125f);
      t2[4]=f2bf(b.x*0.125f); t2[5]=f2bf(b.y*0.125f); t2[6]=f2bf(b.z*0.125f); t2[7]=f2bf(b.w*0.125f);
      qf[s] = __builtin_bit_cast(bf16x8, t2);
    }
  }
  float m[4] = {-1e30f,-1e30f,-1e30f,-1e30f}, lsum[4] = {0,0,0,0};
  f32x4 oacc[4] = {};
  for (int t = 0; t <= qtile; ++t) {
    const int kvb = t * 64;
    #pragma unroll
    for (int j = 0; j < 4; ++j) {
      const int idx = j * 256 + tid, row = idx >> 4, c4 = (idx & 15) * 4;
      const long goff = (long)(kvb + row) * DH + c4;
      float4 kx = *(const float4*)(Kp + goff);
      float4 vx = *(const float4*)(Vp + goff);
      u16x4 kb; kb[0]=f2bf(kx.x); kb[1]=f2bf(kx.y); kb[2]=f2bf(kx.z); kb[3]=f2bf(kx.w);
      *(u16x4*)&Kt[row * FSTR + c4] = kb;
      Vt[(c4+0)*FSTR+row]=f2bf(vx.x); Vt[(c4+1)*FSTR+row]=f2bf(vx.y);
      Vt[(c4+2)*FSTR+row]=f2bf(vx.z); Vt[(c4+3)*FSTR+row]=f2bf(vx.w);
    }
    __syncthreads();
    float sv[16];
    #pragma unroll
    for (int kt = 0; kt < 4; ++kt) {
      bf16x8 kf0 = __builtin_bit_cast(bf16x8, *(const u16x8*)&Kt[(kt*16+l16)*FSTR + lg*8]);
      bf16x8 kf1 = __builtin_bit_cast(bf16x8, *(const u16x8*)&Kt[(kt*16+l16)*FSTR + 32 + lg*8]);
      f32x4 st = {0,0,0,0};
      st = MFMA16(qf[0], kf0, st); st = MFMA16(qf[1], kf1, st);
      const int kg = kvb + kt*16 + l16;
      #pragma unroll
      for (int r = 0; r < 4; ++r) {
        const int qg = qrow0 + lg*4 + r;
        sv[kt*4+r] = (kg > qg) ? -1e30f : st[r];
      }
    }
    float alpha[4], psum[4];
    #pragma unroll
    for (int r = 0; r < 4; ++r) {
      float rm = fmaxf(fmaxf(sv[r], sv[4+r]), fmaxf(sv[8+r], sv[12+r]));
      #pragma unroll
      for (int d = 1; d < 16; d <<= 1) rm = fmaxf(rm, __shfl_xor(rm, d));
      const float mn = fmaxf(m[r], rm);
      alpha[r] = __expf(m[r] - mn); m[r] = mn; psum[r] = 0.f;
    }
    #pragma unroll
    for (int kt = 0; kt < 4; ++kt)
      #pragma unroll
      for (int r = 0; r < 4; ++r) {
        const float p = __expf(sv[kt*4+r] - m[r]);
        psum[r] += p;
        Pt[wave][(lg*4+r)*FSTR + kt*16 + l16] = f2bf(p);
      }
    #pragma unroll
    for (int r = 0; r < 4; ++r) {
      float ps = psum[r];
      #pragma unroll
      for (int d = 1; d < 16; d <<= 1) ps += __shfl_xor(ps, d);
      lsum[r] = lsum[r] * alpha[r] + ps;
    }
    #pragma unroll
    for (int dt = 0; dt < 4; ++dt)
      #pragma unroll
      for (int r = 0; r < 4; ++r) oacc[dt][r] *= alpha[r];
    #pragma unroll
    for (int ks2 = 0; ks2 < 2; ++ks2) {
      bf16x8 pf = __builtin_bit_cast(bf16x8, *(const u16x8*)&Pt[wave][l16*FSTR + ks2*32 + lg*8]);
      #pragma unroll
      for (int dt = 0; dt < 4; ++dt) {
        bf16x8 vf = __builtin_bit_cast(bf16x8, *(const u16x8*)&Vt[(dt*16+l16)*FSTR + ks2*32 + lg*8]);
        oacc[dt] = MFMA16(pf, vf, oacc[dt]);
      }
    }
    __syncthreads();
  }
  #pragma unroll
  for (int r = 0; r < 4; ++r) {
    const float inv = 1.0f / lsum[r];
    float* orow = Op + (long)(qrow0 + lg*4 + r) * DH + l16;
    #pragma unroll
    for (int dt = 0; dt < 4; ++dt) orow[dt*16] = oacc[dt][r] * inv;
  }
}

extern "C" void kernel_launch(void* const* d_in, const int* in_sizes, int n_in,
                              void* d_out, int out_size, void* d_ws, size_t ws_size,
                              hipStream_t stream) {
  (void)in_sizes; (void)n_in; (void)out_size;
  const float* Q = (const float*)d_in[0];
  const float* K = (const float*)d_in[1];
  const float* V = (const float*)d_in[2];
  float* O = (float*)d_out;

  const size_t TSZ = (size_t)BH * SEQ * DH * sizeof(unsigned short);  // 8.39 MB
  if (ws_size >= 2 * TSZ) {
    unsigned short* Kb  = (unsigned short*)d_ws;
    unsigned short* Vtb = Kb + (size_t)BH * SEQ * DH;
    prep_9990093930993<<<dim3(SEQ / 64, BH), dim3(256), 0, stream>>>(K, V, Kb, Vtb);
    attn5_9990093930993<<<dim3(768), dim3(256), 0, stream>>>(Q, Kb, Vtb, O);
  } else {
    attn_fwd_fb_9990093930993<<<dim3(SEQ / 64, BH), dim3(256), 0, stream>>>(Q, K, V, O);
  }
}

// Round 9
// 206.429 us; speedup vs baseline: 1.7740x; 1.7740x over previous
//
#include <hip/hip_runtime.h>

typedef __bf16 bf16x8 __attribute__((ext_vector_type(8)));
typedef unsigned short u16x8 __attribute__((ext_vector_type(8)));
typedef unsigned short u16x4 __attribute__((ext_vector_type(4)));
typedef float f32x4 __attribute__((ext_vector_type(4)));

#define MFMA16(a, b, c) __builtin_amdgcn_mfma_f32_16x16x32_bf16((a), (b), (c), 0, 0, 0)

constexpr int SEQ  = 4096;
constexpr int DH   = 64;
constexpr int BH   = 16;     // B*H
constexpr int LSTR = 72;     // LDS row stride (ushorts): 144B rows, 16B-aligned
constexpr float SCALE_LOG2E = 0.125f * 1.44269504088896f;  // 1/sqrt(64) * log2(e)

__device__ __forceinline__ unsigned short f2bf(float f) {
  unsigned int u = __float_as_uint(f);
  u += 0x7fffu + ((u >> 16) & 1u);   // RNE
  return (unsigned short)(u >> 16);
}

// ---------------- pre-pass: K fp32->bf16 copy; V fp32 -> V^T bf16 tiles (direct, no LDS) ----------------
__global__ __launch_bounds__(256)
void prep_9990093930993(const float* __restrict__ K, const float* __restrict__ V,
                        unsigned short* __restrict__ Kb, unsigned short* __restrict__ Vtb) {
  const int tile = blockIdx.x, bh = blockIdx.y, tid = threadIdx.x;

  // --- K: straight bf16 convert, layout unchanged [bh][S][64] ---
  {
    const int row = tid >> 2;          // 0..63
    const int c0  = (tid & 3) * 16;    // 0,16,32,48
    const float* kr = K + (((long)bh * SEQ + tile * 64) + row) * DH + c0;
    float4 x0 = *(const float4*)(kr);
    float4 x1 = *(const float4*)(kr + 4);
    float4 x2 = *(const float4*)(kr + 8);
    float4 x3 = *(const float4*)(kr + 12);
    u16x8 a, b;
    a[0]=f2bf(x0.x); a[1]=f2bf(x0.y); a[2]=f2bf(x0.z); a[3]=f2bf(x0.w);
    a[4]=f2bf(x1.x); a[5]=f2bf(x1.y); a[6]=f2bf(x1.z); a[7]=f2bf(x1.w);
    b[0]=f2bf(x2.x); b[1]=f2bf(x2.y); b[2]=f2bf(x2.z); b[3]=f2bf(x2.w);
    b[4]=f2bf(x3.x); b[5]=f2bf(x3.y); b[6]=f2bf(x3.z); b[7]=f2bf(x3.w);
    unsigned short* ko = Kb + (((long)bh * SEQ + tile * 64) + row) * DH + c0;
    *(u16x8*)ko = a;
    *(u16x8*)(ko + 8) = b;
  }

  // --- V: direct transpose. lane = d (coalesced reads), wave kg covers 16 keys ---
  {
    const int d  = tid & 63;
    const int kg = tid >> 6;           // 0..3
    const float* vp = V + ((long)bh * SEQ + tile * 64) * DH;
    unsigned short* op = Vtb + (((long)bh * 64 + tile) * 64 + d) * 64 + kg * 16;
    #pragma unroll
    for (int h = 0; h < 2; ++h) {
      u16x8 o;
      #pragma unroll
      for (int j = 0; j < 8; ++j)
        o[j] = f2bf(vp[(kg * 16 + h * 8 + j) * DH + d]);
      *(u16x8*)(op + h * 8) = o;
    }
  }
}

// ---------------- main attention: QBLK=32/wave (128q per block), staged KV, balanced 512-grid ----------------
// Each wave computes 32 q-rows (2 groups of 16); K/V LDS fragment reads are shared
// across both groups -> 1.7x less LDS traffic per q than the 16-row version.
// Grid 512: id<256 -> qsuper s=31-(id>>4) (long first), id>=256 -> s=(id-256)>>4;
// co-resident pairs {c, c+256} sum to 68 tile-iters.
__global__ __launch_bounds__(256, 2)
void attn6_9990093930993(const float* __restrict__ Qg,
                         const unsigned short* __restrict__ Kb,
                         const unsigned short* __restrict__ Vtb,
                         float* __restrict__ Og) {
  __shared__ unsigned short Kt[2][64 * LSTR];
  __shared__ unsigned short Vt[2][64 * LSTR];
  __shared__ unsigned short Pt[4][32 * LSTR];

  const int tid  = threadIdx.x;
  const int wave = tid >> 6;
  const int lane = tid & 63;
  const int l16  = lane & 15;
  const int lg   = lane >> 4;

  // ---- decode work: qsuper s (128 q-rows), bh ----
  int s, bhi;
  {
    const int id = blockIdx.x;
    if (id < 256) { s = 31 - (id >> 4); bhi = id & 15; }
    else          { const int j = id - 256; s = j >> 4; bhi = j & 15; }
  }
  const long bh = bhi;
  const int  qt = 2 * s + 1;             // last k-tile index

  const float*          Qp = Qg  + bh * (long)(SEQ * DH);
  const unsigned short* Kp = Kb  + bh * (long)(SEQ * DH);
  const unsigned short* Vp = Vtb + bh * (long)(SEQ * DH);
  float*                Op = Og  + bh * (long)(SEQ * DH);

  const int qrow0 = s * 128 + wave * 32;   // wave's 32 q-rows

  const int srow = tid >> 2;
  const int scol = (tid & 3) * 16;
  const int f    = tid * 16;

  // all-ones bf16 B-fragment: accl = P * ones -> row sums of P
  bf16x8 vone;
  {
    u16x8 t1;
    #pragma unroll
    for (int j = 0; j < 8; ++j) t1[j] = 0x3F80;
    vone = __builtin_bit_cast(bf16x8, t1);
  }

  // Q fragments for both 16-row groups (fp32 -> bf16 inline, scale*log2e folded)
  bf16x8 qf[2][2];
  #pragma unroll
  for (int g = 0; g < 2; ++g) {
    const float* qr = Qp + (long)(qrow0 + g * 16 + l16) * DH + lg * 8;
    #pragma unroll
    for (int h = 0; h < 2; ++h) {
      float4 a = *(const float4*)(qr + h * 32);
      float4 b = *(const float4*)(qr + h * 32 + 4);
      u16x8 t2;
      t2[0] = f2bf(a.x * SCALE_LOG2E); t2[1] = f2bf(a.y * SCALE_LOG2E);
      t2[2] = f2bf(a.z * SCALE_LOG2E); t2[3] = f2bf(a.w * SCALE_LOG2E);
      t2[4] = f2bf(b.x * SCALE_LOG2E); t2[5] = f2bf(b.y * SCALE_LOG2E);
      t2[6] = f2bf(b.z * SCALE_LOG2E); t2[7] = f2bf(b.w * SCALE_LOG2E);
      qf[g][h] = __builtin_bit_cast(bf16x8, t2);
    }
  }
  const int qdiag0 = (qrow0) >> 6;          // diagonal k-tile for group 0
  const int qdiag1 = (qrow0 + 16) >> 6;     // and group 1

  f32x4 oacc0[4] = {}, oacc1[4] = {};
  f32x4 accl0 = {}, accl1 = {};

  u16x8 pk0, pk1, pv0, pv1;   // prefetch registers
  pk0 = *(const u16x8*)(Kp + f); pk1 = *(const u16x8*)(Kp + f + 8);
  pv0 = *(const u16x8*)(Vp + f); pv1 = *(const u16x8*)(Vp + f + 8);

  #pragma unroll 1
  for (int t = 0; t <= qt; ++t) {
    const int buf = t & 1;
    *(u16x8*)&Kt[buf][srow * LSTR + scol]     = pk0;
    *(u16x8*)&Kt[buf][srow * LSTR + scol + 8] = pk1;
    *(u16x8*)&Vt[buf][srow * LSTR + scol]     = pv0;
    *(u16x8*)&Vt[buf][srow * LSTR + scol + 8] = pv1;
    __syncthreads();

    if (t < qt) {   // issue next tile's loads; latency hides under compute
      const unsigned short* ks = Kp + (long)(t + 1) * 4096;
      const unsigned short* vs = Vp + (long)(t + 1) * 4096;
      pk0 = *(const u16x8*)(ks + f); pk1 = *(const u16x8*)(ks + f + 8);
      pv0 = *(const u16x8*)(vs + f); pv1 = *(const u16x8*)(vs + f + 8);
    }

    // ---- QK^T (swapped: A=K, B=Q) + exp2 + P-write, per kt; kf reads shared by both groups ----
    #pragma unroll
    for (int kt = 0; kt < 4; ++kt) {
      const bf16x8 kf0 = __builtin_bit_cast(bf16x8, *(const u16x8*)&Kt[buf][(kt*16 + l16) * LSTR + lg * 8]);
      const bf16x8 kf1 = __builtin_bit_cast(bf16x8, *(const u16x8*)&Kt[buf][(kt*16 + l16) * LSTR + 32 + lg * 8]);
      const int k0 = t * 64 + kt * 16 + lg * 4;
      #pragma unroll
      for (int g = 0; g < 2; ++g) {
        f32x4 st = {0.f, 0.f, 0.f, 0.f};
        st = MFMA16(kf0, qf[g][0], st);
        st = MFMA16(kf1, qf[g][1], st);
        // lane holds S[q = qrow0+g*16+l16][k = k0+r]
        if (t >= (g ? qdiag1 : qdiag0)) {   // diagonal or beyond: causal mask
          const int qg = qrow0 + g * 16 + l16;
          #pragma unroll
          for (int r = 0; r < 4; ++r)
            if (k0 + r > qg) st[r] = -1e30f;
        }
        u16x4 w;
        w[0] = f2bf(__builtin_amdgcn_exp2f(st[0]));
        w[1] = f2bf(__builtin_amdgcn_exp2f(st[1]));
        w[2] = f2bf(__builtin_amdgcn_exp2f(st[2]));
        w[3] = f2bf(__builtin_amdgcn_exp2f(st[3]));
        *(u16x4*)&Pt[wave][(g * 16 + l16) * LSTR + kt * 16 + lg * 4] = w;
      }
    }

    // ---- O += P V ; lsum += P * ones. vf reads shared by both groups ----
    #pragma unroll
    for (int ks2 = 0; ks2 < 2; ++ks2) {
      const bf16x8 pf0 = __builtin_bit_cast(bf16x8, *(const u16x8*)&Pt[wave][l16 * LSTR + ks2 * 32 + lg * 8]);
      const bf16x8 pf1 = __builtin_bit_cast(bf16x8, *(const u16x8*)&Pt[wave][(16 + l16) * LSTR + ks2 * 32 + lg * 8]);
      accl0 = MFMA16(pf0, vone, accl0);
      accl1 = MFMA16(pf1, vone, accl1);
      #pragma unroll
      for (int dt = 0; dt < 4; ++dt) {
        const bf16x8 vf = __builtin_bit_cast(bf16x8, *(const u16x8*)&Vt[buf][(dt*16 + l16) * LSTR + ks2 * 32 + lg * 8]);
        oacc0[dt] = MFMA16(pf0, vf, oacc0[dt]);
        oacc1[dt] = MFMA16(pf1, vf, oacc1[dt]);
      }
    }
    // no trailing barrier: double buffer + next iteration's leading barrier covers the hazard
  }

  // ---- epilogue: normalize by row-sum and store (both groups) ----
  #pragma unroll
  for (int r = 0; r < 4; ++r) {
    const float inv0 = 1.0f / accl0[r];
    const float inv1 = 1.0f / accl1[r];
    float* orow0 = Op + (long)(qrow0 + lg * 4 + r) * DH + l16;
    float* orow1 = Op + (long)(qrow0 + 16 + lg * 4 + r) * DH + l16;
    #pragma unroll
    for (int dt = 0; dt < 4; ++dt) {
      orow0[dt * 16] = oacc0[dt][r] * inv0;
      orow1[dt * 16] = oacc1[dt][r] * inv1;
    }
  }
}

// ---------------- fallback (fp32 direct, if workspace too small) ----------------
__global__ __launch_bounds__(256, 2)
void attn_fwd_fb_9990093930993(const float* __restrict__ Qg, const float* __restrict__ Kg,
                               const float* __restrict__ Vg, float* __restrict__ Og) {
  constexpr int FSTR = 88;
  __shared__ unsigned short Kt[64 * FSTR];
  __shared__ unsigned short Vt[64 * FSTR];
  __shared__ unsigned short Pt[4][16 * FSTR];
  const int tid = threadIdx.x, wave = tid >> 6, lane = tid & 63;
  const int l16 = lane & 15, lg = lane >> 4;
  const int qtile = blockIdx.x; const long bh = blockIdx.y;
  const float* Qp = Qg + bh * (long)(SEQ * DH);
  const float* Kp = Kg + bh * (long)(SEQ * DH);
  const float* Vp = Vg + bh * (long)(SEQ * DH);
  float* Op = Og + bh * (long)(SEQ * DH);
  const int qrow0 = qtile * 64 + wave * 16;
  bf16x8 qf[2];
  {
    const float* qr = Qp + (long)(qrow0 + l16) * DH + lg * 8;
    #pragma unroll
    for (int s = 0; s < 2; ++s) {
      float4 a = *(const float4*)(qr + s * 32);
      float4 b = *(const float4*)(qr + s * 32 + 4);
      u16x8 t2;
      t2[0]=f2bf(a.x*0.125f); t2[1]=f2bf(a.y*0.125f); t2[2]=f2bf(a.z*0.125f); t2[3]=f2bf(a.w*0.125f);
      t2[4]=f2bf(b.x*0.125f); t2[5]=f2bf(b.y*0.125f); t2[6]=f2bf(b.z*0.125f); t2[7]=f2bf(b.w*0.125f);
      qf[s] = __builtin_bit_cast(bf16x8, t2);
    }
  }
  float m[4] = {-1e30f,-1e30f,-1e30f,-1e30f}, lsum[4] = {0,0,0,0};
  f32x4 oacc[4] = {};
  for (int t = 0; t <= qtile; ++t) {
    const int kvb = t * 64;
    #pragma unroll
    for (int j = 0; j < 4; ++j) {
      const int idx = j * 256 + tid, row = idx >> 4, c4 = (idx & 15) * 4;
      const long goff = (long)(kvb + row) * DH + c4;
      float4 kx = *(const float4*)(Kp + goff);
      float4 vx = *(const float4*)(Vp + goff);
      u16x4 kb; kb[0]=f2bf(kx.x); kb[1]=f2bf(kx.y); kb[2]=f2bf(kx.z); kb[3]=f2bf(kx.w);
      *(u16x4*)&Kt[row * FSTR + c4] = kb;
      Vt[(c4+0)*FSTR+row]=f2bf(vx.x); Vt[(c4+1)*FSTR+row]=f2bf(vx.y);
      Vt[(c4+2)*FSTR+row]=f2bf(vx.z); Vt[(c4+3)*FSTR+row]=f2bf(vx.w);
    }
    __syncthreads();
    float sv[16];
    #pragma unroll
    for (int kt = 0; kt < 4; ++kt) {
      bf16x8 kf0 = __builtin_bit_cast(bf16x8, *(const u16x8*)&Kt[(kt*16+l16)*FSTR + lg*8]);
      bf16x8 kf1 = __builtin_bit_cast(bf16x8, *(const u16x8*)&Kt[(kt*16+l16)*FSTR + 32 + lg*8]);
      f32x4 st = {0,0,0,0};
      st = MFMA16(qf[0], kf0, st); st = MFMA16(qf[1], kf1, st);
      const int kg = kvb + kt*16 + l16;
      #pragma unroll
      for (int r = 0; r < 4; ++r) {
        const int qg = qrow0 + lg*4 + r;
        sv[kt*4+r] = (kg > qg) ? -1e30f : st[r];
      }
    }
    float alpha[4], psum[4];
    #pragma unroll
    for (int r = 0; r < 4; ++r) {
      float rm = fmaxf(fmaxf(sv[r], sv[4+r]), fmaxf(sv[8+r], sv[12+r]));
      #pragma unroll
      for (int d = 1; d < 16; d <<= 1) rm = fmaxf(rm, __shfl_xor(rm, d));
      const float mn = fmaxf(m[r], rm);
      alpha[r] = __expf(m[r] - mn); m[r] = mn; psum[r] = 0.f;
    }
    #pragma unroll
    for (int kt = 0; kt < 4; ++kt)
      #pragma unroll
      for (int r = 0; r < 4; ++r) {
        const float p = __expf(sv[kt*4+r] - m[r]);
        psum[r] += p;
        Pt[wave][(lg*4+r)*FSTR + kt*16 + l16] = f2bf(p);
      }
    #pragma unroll
    for (int r = 0; r < 4; ++r) {
      float ps = psum[r];
      #pragma unroll
      for (int d = 1; d < 16; d <<= 1) ps += __shfl_xor(ps, d);
      lsum[r] = lsum[r] * alpha[r] + ps;
    }
    #pragma unroll
    for (int dt = 0; dt < 4; ++dt)
      #pragma unroll
      for (int r = 0; r < 4; ++r) oacc[dt][r] *= alpha[r];
    #pragma unroll
    for (int ks2 = 0; ks2 < 2; ++ks2) {
      bf16x8 pf = __builtin_bit_cast(bf16x8, *(const u16x8*)&Pt[wave][l16*FSTR + ks2*32 + lg*8]);
      #pragma unroll
      for (int dt = 0; dt < 4; ++dt) {
        bf16x8 vf = __builtin_bit_cast(bf16x8, *(const u16x8*)&Vt[(dt*16+l16)*FSTR + ks2*32 + lg*8]);
        oacc[dt] = MFMA16(pf, vf, oacc[dt]);
      }
    }
    __syncthreads();
  }
  #pragma unroll
  for (int r = 0; r < 4; ++r) {
    const float inv = 1.0f / lsum[r];
    float* orow = Op + (long)(qrow0 + lg*4 + r) * DH + l16;
    #pragma unroll
    for (int dt = 0; dt < 4; ++dt) orow[dt*16] = oacc[dt][r] * inv;
  }
}

extern "C" void kernel_launch(void* const* d_in, const int* in_sizes, int n_in,
                              void* d_out, int out_size, void* d_ws, size_t ws_size,
                              hipStream_t stream) {
  (void)in_sizes; (void)n_in; (void)out_size;
  const float* Q = (const float*)d_in[0];
  const float* K = (const float*)d_in[1];
  const float* V = (const float*)d_in[2];
  float* O = (float*)d_out;

  const size_t TSZ = (size_t)BH * SEQ * DH * sizeof(unsigned short);  // 8.39 MB
  if (ws_size >= 2 * TSZ) {
    unsigned short* Kb  = (unsigned short*)d_ws;
    unsigned short* Vtb = Kb + (size_t)BH * SEQ * DH;
    prep_9990093930993<<<dim3(SEQ / 64, BH), dim3(256), 0, stream>>>(K, V, Kb, Vtb);
    attn6_9990093930993<<<dim3(512), dim3(256), 0, stream>>>(Q, Kb, Vtb, O);
  } else {
    attn_fwd_fb_9990093930993<<<dim3(SEQ / 64, BH), dim3(256), 0, stream>>>(Q, K, V, O);
  }
}

// Round 10
// 200.616 us; speedup vs baseline: 1.8254x; 1.0290x over previous
//
#include <hip/hip_runtime.h>

typedef __bf16 bf16x8 __attribute__((ext_vector_type(8)));
typedef unsigned short u16x8 __attribute__((ext_vector_type(8)));
typedef unsigned short u16x4 __attribute__((ext_vector_type(4)));
typedef float f32x4 __attribute__((ext_vector_type(4)));

#define MFMA16(a, b, c) __builtin_amdgcn_mfma_f32_16x16x32_bf16((a), (b), (c), 0, 0, 0)

constexpr int SEQ  = 4096;
constexpr int DH   = 64;
constexpr int BH   = 16;     // B*H
constexpr int LSTR = 72;     // LDS row stride (ushorts): 144B rows, 16B-aligned
constexpr float SCALE_LOG2E = 0.125f * 1.44269504088896f;  // 1/sqrt(64) * log2(e)

__device__ __forceinline__ unsigned short f2bf(float f) {
  unsigned int u = __float_as_uint(f);
  u += 0x7fffu + ((u >> 16) & 1u);   // RNE
  return (unsigned short)(u >> 16);
}

// ---------------- pre-pass: K fp32->bf16 copy; V fp32 -> V^T bf16 tiles (direct, no LDS) ----------------
__global__ __launch_bounds__(256)
void prep_9990093930993(const float* __restrict__ K, const float* __restrict__ V,
                        unsigned short* __restrict__ Kb, unsigned short* __restrict__ Vtb) {
  const int tile = blockIdx.x, bh = blockIdx.y, tid = threadIdx.x;

  // --- K: straight bf16 convert, layout unchanged [bh][S][64] ---
  {
    const int row = tid >> 2;          // 0..63
    const int c0  = (tid & 3) * 16;    // 0,16,32,48
    const float* kr = K + (((long)bh * SEQ + tile * 64) + row) * DH + c0;
    float4 x0 = *(const float4*)(kr);
    float4 x1 = *(const float4*)(kr + 4);
    float4 x2 = *(const float4*)(kr + 8);
    float4 x3 = *(const float4*)(kr + 12);
    u16x8 a, b;
    a[0]=f2bf(x0.x); a[1]=f2bf(x0.y); a[2]=f2bf(x0.z); a[3]=f2bf(x0.w);
    a[4]=f2bf(x1.x); a[5]=f2bf(x1.y); a[6]=f2bf(x1.z); a[7]=f2bf(x1.w);
    b[0]=f2bf(x2.x); b[1]=f2bf(x2.y); b[2]=f2bf(x2.z); b[3]=f2bf(x2.w);
    b[4]=f2bf(x3.x); b[5]=f2bf(x3.y); b[6]=f2bf(x3.z); b[7]=f2bf(x3.w);
    unsigned short* ko = Kb + (((long)bh * SEQ + tile * 64) + row) * DH + c0;
    *(u16x8*)ko = a;
    *(u16x8*)(ko + 8) = b;
  }

  // --- V: direct transpose. lane = d (coalesced reads), wave kg covers 16 keys ---
  {
    const int d  = tid & 63;
    const int kg = tid >> 6;           // 0..3
    const float* vp = V + ((long)bh * SEQ + tile * 64) * DH;
    unsigned short* op = Vtb + (((long)bh * 64 + tile) * 64 + d) * 64 + kg * 16;
    #pragma unroll
    for (int h = 0; h < 2; ++h) {
      u16x8 o;
      #pragma unroll
      for (int j = 0; j < 8; ++j)
        o[j] = f2bf(vp[(kg * 16 + h * 8 + j) * DH + d]);
      *(u16x8*)(op + h * 8) = o;
    }
  }
}

// ---------------- main attention: round-7 base + DEFERRED PV (PV(t-1) overlaps QK(t)) ----------------
// Grid = 768 blocks: qtiles 32..63 singles (two id-ranges), qtiles 0..31 paired {p,31-p}.
// Per iteration: stage(t) -> barrier -> prefetch(t+1) -> PV(t-1) [independent MFMAs]
// -> QK(t) -> exp2 -> P-write. The QK->softmax->P->PV serial spine is broken: exp2's
// consumer (PV) moved to the next iteration (~1 iter of slack).
// Hazards (1 barrier/iter): Kt/Vt[x] rewritten at t+2 are fenced from iter-t readers by
// barriers t+1,t+2; Pt read(t-1)-then-write(t) is same-wave program order.
__global__ __launch_bounds__(256, 3)
void attn7_9990093930993(const float* __restrict__ Qg,
                         const unsigned short* __restrict__ Kb,
                         const unsigned short* __restrict__ Vtb,
                         float* __restrict__ Og) {
  __shared__ unsigned short Kt[2][64 * LSTR];
  __shared__ unsigned short Vt[2][64 * LSTR];
  __shared__ unsigned short Pt[4][16 * LSTR];

  const int tid  = threadIdx.x;
  const int wave = tid >> 6;
  const int lane = tid & 63;
  const int l16  = lane & 15;
  const int lg   = lane >> 4;

  // ---- decode balanced work assignment (bijection onto qtile 0..63 x bh 0..15) ----
  int nseg, qt0, qt1 = 0, bhi;
  {
    const int id = blockIdx.x;
    if (id < 256)      { nseg = 1; qt0 = 63 - (id >> 3); bhi = id & 7; }
    else if (id < 512) { const int j = id - 256; nseg = 2; const int p = j >> 4;
                         qt0 = 31 - p; qt1 = p; bhi = j & 15; }
    else               { const int j = id - 512; nseg = 1; qt0 = 32 + (j >> 3); bhi = 8 + (j & 7); }
  }
  const long bh = bhi;

  const float*          Qp = Qg  + bh * (long)(SEQ * DH);
  const unsigned short* Kp = Kb  + bh * (long)(SEQ * DH);
  const unsigned short* Vp = Vtb + bh * (long)(SEQ * DH);
  float*                Op = Og  + bh * (long)(SEQ * DH);

  const int srow = tid >> 2;
  const int scol = (tid & 3) * 16;
  const int f    = tid * 16;

  // all-ones bf16 B-fragment: accl = P * ones -> row sums of P
  bf16x8 vone;
  {
    u16x8 t1;
    #pragma unroll
    for (int j = 0; j < 8; ++j) t1[j] = 0x3F80;
    vone = __builtin_bit_cast(bf16x8, t1);
  }

  u16x8 pk0, pk1, pv0, pv1;   // prefetch registers

  #pragma unroll 1
  for (int seg = 0; seg < nseg; ++seg) {
    const int qt = (seg == 0) ? qt0 : qt1;
    const int qrow0 = qt * 64 + wave * 16;

    // Q fragments (inline fp32 -> bf16, scale*log2e folded); MFMA B-operand (swapped QK^T)
    bf16x8 qf[2];
    {
      const float* qr = Qp + (long)(qrow0 + l16) * DH + lg * 8;
      #pragma unroll
      for (int s = 0; s < 2; ++s) {
        float4 a = *(const float4*)(qr + s * 32);
        float4 b = *(const float4*)(qr + s * 32 + 4);
        u16x8 t2;
        t2[0] = f2bf(a.x * SCALE_LOG2E); t2[1] = f2bf(a.y * SCALE_LOG2E);
        t2[2] = f2bf(a.z * SCALE_LOG2E); t2[3] = f2bf(a.w * SCALE_LOG2E);
        t2[4] = f2bf(b.x * SCALE_LOG2E); t2[5] = f2bf(b.y * SCALE_LOG2E);
        t2[6] = f2bf(b.z * SCALE_LOG2E); t2[7] = f2bf(b.w * SCALE_LOG2E);
        qf[s] = __builtin_bit_cast(bf16x8, t2);
      }
    }

    f32x4 oacc[4] = {};
    f32x4 accl    = {};

    // prefetch tile 0
    pk0 = *(const u16x8*)(Kp + f); pk1 = *(const u16x8*)(Kp + f + 8);
    pv0 = *(const u16x8*)(Vp + f); pv1 = *(const u16x8*)(Vp + f + 8);

    #pragma unroll 1
    for (int t = 0; t <= qt; ++t) {
      const int buf = t & 1;
      *(u16x8*)&Kt[buf][srow * LSTR + scol]     = pk0;
      *(u16x8*)&Kt[buf][srow * LSTR + scol + 8] = pk1;
      *(u16x8*)&Vt[buf][srow * LSTR + scol]     = pv0;
      *(u16x8*)&Vt[buf][srow * LSTR + scol + 8] = pv1;
      __syncthreads();

      if (t < qt) {   // issue next tile's loads; latency hides under compute
        const unsigned short* ks = Kp + (long)(t + 1) * 4096;
        const unsigned short* vs = Vp + (long)(t + 1) * 4096;
        pk0 = *(const u16x8*)(ks + f); pk1 = *(const u16x8*)(ks + f + 8);
        pv0 = *(const u16x8*)(vs + f); pv1 = *(const u16x8*)(vs + f + 8);
      }

      // ---- PV(t-1): independent of this iter's QK — fills the MFMA pipe while
      //      QK's ds_reads are in flight. Reads Pt (same wave, written last iter)
      //      and Vt[buf^1] (staged last iter; rewrite fenced by barriers t+1,t+2).
      if (t > 0) {
        #pragma unroll
        for (int ks2 = 0; ks2 < 2; ++ks2) {
          const bf16x8 pf = __builtin_bit_cast(bf16x8, *(const u16x8*)&Pt[wave][l16 * LSTR + ks2 * 32 + lg * 8]);
          accl = MFMA16(pf, vone, accl);
          #pragma unroll
          for (int dt = 0; dt < 4; ++dt) {
            const bf16x8 vf = __builtin_bit_cast(bf16x8, *(const u16x8*)&Vt[buf ^ 1][(dt*16 + l16) * LSTR + ks2 * 32 + lg * 8]);
            oacc[dt] = MFMA16(pf, vf, oacc[dt]);
          }
        }
      }

      // ---- S^T = K Q^T (swapped): lane holds S[q=l16][k = t*64+kt*16+lg*4+r] ----
      float sv[16];
      #pragma unroll
      for (int kt = 0; kt < 4; ++kt) {
        bf16x8 kf0 = __builtin_bit_cast(bf16x8, *(const u16x8*)&Kt[buf][(kt*16 + l16) * LSTR + lg * 8]);
        bf16x8 kf1 = __builtin_bit_cast(bf16x8, *(const u16x8*)&Kt[buf][(kt*16 + l16) * LSTR + 32 + lg * 8]);
        f32x4 st = {0.f, 0.f, 0.f, 0.f};
        st = MFMA16(kf0, qf[0], st);
        st = MFMA16(kf1, qf[1], st);
        #pragma unroll
        for (int r = 0; r < 4; ++r) sv[kt * 4 + r] = st[r];
      }
      if (t == qt) {   // diagonal tile mask: k > q
        const int qg = qrow0 + l16;
        #pragma unroll
        for (int kt = 0; kt < 4; ++kt) {
          const int k0 = t * 64 + kt * 16 + lg * 4;
          #pragma unroll
          for (int r = 0; r < 4; ++r)
            if (k0 + r > qg) sv[kt * 4 + r] = -1e30f;
        }
      }

      // ---- p = exp2(s); 4 k-consecutive bf16 per lane; one b64 LDS write per kt.
      //      Consumer is NEXT iteration's PV -> off the critical path.
      #pragma unroll
      for (int kt = 0; kt < 4; ++kt) {
        u16x4 w;
        w[0] = f2bf(__builtin_amdgcn_exp2f(sv[kt * 4 + 0]));
        w[1] = f2bf(__builtin_amdgcn_exp2f(sv[kt * 4 + 1]));
        w[2] = f2bf(__builtin_amdgcn_exp2f(sv[kt * 4 + 2]));
        w[3] = f2bf(__builtin_amdgcn_exp2f(sv[kt * 4 + 3]));
        *(u16x4*)&Pt[wave][l16 * LSTR + kt * 16 + lg * 4] = w;
      }
      // no trailing barrier
    }

    // ---- final PV(qt): Vt[qt&1] untouched since its stage ----
    #pragma unroll
    for (int ks2 = 0; ks2 < 2; ++ks2) {
      const bf16x8 pf = __builtin_bit_cast(bf16x8, *(const u16x8*)&Pt[wave][l16 * LSTR + ks2 * 32 + lg * 8]);
      accl = MFMA16(pf, vone, accl);
      #pragma unroll
      for (int dt = 0; dt < 4; ++dt) {
        const bf16x8 vf = __builtin_bit_cast(bf16x8, *(const u16x8*)&Vt[qt & 1][(dt*16 + l16) * LSTR + ks2 * 32 + lg * 8]);
        oacc[dt] = MFMA16(pf, vf, oacc[dt]);
      }
    }

    // ---- epilogue: normalize by row-sum and store ----
    #pragma unroll
    for (int r = 0; r < 4; ++r) {
      const float inv = 1.0f / accl[r];
      float* orow = Op + (long)(qrow0 + lg * 4 + r) * DH + l16;
      #pragma unroll
      for (int dt = 0; dt < 4; ++dt)
        orow[dt * 16] = oacc[dt][r] * inv;
    }
    __syncthreads();   // all waves' final-PV reads done before next segment's first write
  }
}

// ---------------- fallback (fp32 direct, if workspace too small) ----------------
__global__ __launch_bounds__(256, 2)
void attn_fwd_fb_9990093930993(const float* __restrict__ Qg, const float* __restrict__ Kg,
                               const float* __restrict__ Vg, float* __restrict__ Og) {
  constexpr int FSTR = 88;
  __shared__ unsigned short Kt[64 * FSTR];
  __shared__ unsigned short Vt[64 * FSTR];
  __shared__ unsigned short Pt[4][16 * FSTR];
  const int tid = threadIdx.x, wave = tid >> 6, lane = tid & 63;
  const int l16 = lane & 15, lg = lane >> 4;
  const int qtile = blockIdx.x; const long bh = blockIdx.y;
  const float* Qp = Qg + bh * (long)(SEQ * DH);
  const float* Kp = Kg + bh * (long)(SEQ * DH);
  const float* Vp = Vg + bh * (long)(SEQ * DH);
  float* Op = Og + bh * (long)(SEQ * DH);
  const int qrow0 = qtile * 64 + wave * 16;
  bf16x8 qf[2];
  {
    const float* qr = Qp + (long)(qrow0 + l16) * DH + lg * 8;
    #pragma unroll
    for (int s = 0; s < 2; ++s) {
      float4 a = *(const float4*)(qr + s * 32);
      float4 b = *(const float4*)(qr + s * 32 + 4);
      u16x8 t2;
      t2[0]=f2bf(a.x*0.125f); t2[1]=f2bf(a.y*0.125f); t2[2]=f2bf(a.z*0.125f); t2[3]=f2bf(a.w*0.125f);
      t2[4]=f2bf(b.x*0.125f); t2[5]=f2bf(b.y*0.125f); t2[6]=f2bf(b.z*0.125f); t2[7]=f2bf(b.w*0.125f);
      qf[s] = __builtin_bit_cast(bf16x8, t2);
    }
  }
  float m[4] = {-1e30f,-1e30f,-1e30f,-1e30f}, lsum[4] = {0,0,0,0};
  f32x4 oacc[4] = {};
  for (int t = 0; t <= qtile; ++t) {
    const int kvb = t * 64;
    #pragma unroll
    for (int j = 0; j < 4; ++j) {
      const int idx = j * 256 + tid, row = idx >> 4, c4 = (idx & 15) * 4;
      const long goff = (long)(kvb + row) * DH + c4;
      float4 kx = *(const float4*)(Kp + goff);
      float4 vx = *(const float4*)(Vp + goff);
      u16x4 kb; kb[0]=f2bf(kx.x); kb[1]=f2bf(kx.y); kb[2]=f2bf(kx.z); kb[3]=f2bf(kx.w);
      *(u16x4*)&Kt[row * FSTR + c4] = kb;
      Vt[(c4+0)*FSTR+row]=f2bf(vx.x); Vt[(c4+1)*FSTR+row]=f2bf(vx.y);
      Vt[(c4+2)*FSTR+row]=f2bf(vx.z); Vt[(c4+3)*FSTR+row]=f2bf(vx.w);
    }
    __syncthreads();
    float sv[16];
    #pragma unroll
    for (int kt = 0; kt < 4; ++kt) {
      bf16x8 kf0 = __builtin_bit_cast(bf16x8, *(const u16x8*)&Kt[(kt*16+l16)*FSTR + lg*8]);
      bf16x8 kf1 = __builtin_bit_cast(bf16x8, *(const u16x8*)&Kt[(kt*16+l16)*FSTR + 32 + lg*8]);
      f32x4 st = {0,0,0,0};
      st = MFMA16(qf[0], kf0, st); st = MFMA16(qf[1], kf1, st);
      const int kg = kvb + kt*16 + l16;
      #pragma unroll
      for (int r = 0; r < 4; ++r) {
        const int qg = qrow0 + lg*4 + r;
        sv[kt*4+r] = (kg > qg) ? -1e30f : st[r];
      }
    }
    float alpha[4], psum[4];
    #pragma unroll
    for (int r = 0; r < 4; ++r) {
      float rm = fmaxf(fmaxf(sv[r], sv[4+r]), fmaxf(sv[8+r], sv[12+r]));
      #pragma unroll
      for (int d = 1; d < 16; d <<= 1) rm = fmaxf(rm, __shfl_xor(rm, d));
      const float mn = fmaxf(m[r], rm);
      alpha[r] = __expf(m[r] - mn); m[r] = mn; psum[r] = 0.f;
    }
    #pragma unroll
    for (int kt = 0; kt < 4; ++kt)
      #pragma unroll
      for (int r = 0; r < 4; ++r) {
        const float p = __expf(sv[kt*4+r] - m[r]);
        psum[r] += p;
        Pt[wave][(lg*4+r)*FSTR + kt*16 + l16] = f2bf(p);
      }
    #pragma unroll
    for (int r = 0; r < 4; ++r) {
      float ps = psum[r];
      #pragma unroll
      for (int d = 1; d < 16; d <<= 1) ps += __shfl_xor(ps, d);
      lsum[r] = lsum[r] * alpha[r] + ps;
    }
    #pragma unroll
    for (int dt = 0; dt < 4; ++dt)
      #pragma unroll
      for (int r = 0; r < 4; ++r) oacc[dt][r] *= alpha[r];
    #pragma unroll
    for (int ks2 = 0; ks2 < 2; ++ks2) {
      bf16x8 pf = __builtin_bit_cast(bf16x8, *(const u16x8*)&Pt[wave][l16*FSTR + ks2*32 + lg*8]);
      #pragma unroll
      for (int dt = 0; dt < 4; ++dt) {
        bf16x8 vf = __builtin_bit_cast(bf16x8, *(const u16x8*)&Vt[(dt*16+l16)*FSTR + ks2*32 + lg*8]);
        oacc[dt] = MFMA16(pf, vf, oacc[dt]);
      }
    }
    __syncthreads();
  }
  #pragma unroll
  for (int r = 0; r < 4; ++r) {
    const float inv = 1.0f / lsum[r];
    float* orow = Op + (long)(qrow0 + lg*4 + r) * DH + l16;
    #pragma unroll
    for (int dt = 0; dt < 4; ++dt) orow[dt*16] = oacc[dt][r] * inv;
  }
}

extern "C" void kernel_launch(void* const* d_in, const int* in_sizes, int n_in,
                              void* d_out, int out_size, void* d_ws, size_t ws_size,
                              hipStream_t stream) {
  (void)in_sizes; (void)n_in; (void)out_size;
  const float* Q = (const float*)d_in[0];
  const float* K = (const float*)d_in[1];
  const float* V = (const float*)d_in[2];
  float* O = (float*)d_out;

  const size_t TSZ = (size_t)BH * SEQ * DH * sizeof(unsigned short);  // 8.39 MB
  if (ws_size >= 2 * TSZ) {
    unsigned short* Kb  = (unsigned short*)d_ws;
    unsigned short* Vtb = Kb + (size_t)BH * SEQ * DH;
    prep_9990093930993<<<dim3(SEQ / 64, BH), dim3(256), 0, stream>>>(K, V, Kb, Vtb);
    attn7_9990093930993<<<dim3(768), dim3(256), 0, stream>>>(Q, Kb, Vtb, O);
  } else {
    attn_fwd_fb_9990093930993<<<dim3(SEQ / 64, BH), dim3(256), 0, stream>>>(Q, K, V, O);
  }
}